// Round 5
// baseline (1445.545 us; speedup 1.0000x reference)
//
#include <hip/hip_runtime.h>
#include <math.h>

#define NPFS   4
#define NFM    512
#define NP     256
#define BATCH  128
#define NBLK   (BATCH * NPFS)   // 512 pfaffians
#define THREADS 512
#define MAXB   17               // max owned float4-blocks per thread

// Register-resident Pfaffian, self-contained steps (no cross-step LDS state):
//  - group g = tid>>2 (4 threads) owns rows {g, 255-g} (g==0: row 255 only);
//    rows padded to 4 floats; pair totals <= 65 float4 blocks.
//  - thread h = tid&3 owns blocks pos with pos%4==h -> <= 17 float4 in VGPRs.
//  - per step: (A) owners publish columns k,k+1 -> ck/cp; (B) argmax;
//    (C) stage pre-swap row kp -> A2, col kp -> A3; (D) apply swap to
//    registers + publish tau/v; (E) rank-2 register update.
//  - dead elements (columns <= k+1, rows <= k+1, padding) are never read.

__device__ __forceinline__ float lane_ex(float4 q, int l) {
    float r = q.x;
    r = (l == 1) ? q.y : r;
    r = (l == 2) ? q.z : r;
    r = (l == 3) ? q.w : r;
    return r;
}

extern "C" __global__ __launch_bounds__(THREADS, 4)
void MultiPf_32469952758284_kernel(const float* __restrict__ F,
                                   const int* __restrict__ idx,
                                   float* __restrict__ ws)
{
    __shared__ float ck[NP];        // column k   (fresh each step)
    __shared__ float cp[NP];        // column k+1 (fresh each step)
    __shared__ float tv[2 * NP];    // tv[2c]=tau[c], tv[2c+1]=v[c]
    __shared__ float A2[NP];        // pre-swap row kp: A2[c]=L[kp][c], c in [p,kp)
    __shared__ float A3[NP];        // pre-swap col kp: A3[r]=L[r][kp], r > kp
    __shared__ int   idxL[NP];
    __shared__ float red[8];
    __shared__ float sred[8];
    __shared__ int   redi[8];

    const int tid = threadIdx.x;
    const int bid = blockIdx.x;
    const int b = bid >> 2, s = bid & 3;
    const float* __restrict__ Fs = F + (size_t)s * NFM * NFM;

    const int g  = tid >> 2, h = tid & 3;
    const int R0 = (g == 0) ? 255 : g;
    const int R1 = (g == 0) ? -1  : 255 - g;
    const int nb0 = (R0 + 3) >> 2;
    const int nbT = nb0 + ((g == 0) ? 0 : ((R1 + 3) >> 2));

    if (tid < NP) idxL[tid] = idx[b * NP + tid];
    __syncthreads();

    // ---- gather owned blocks into registers
    float4 Lb[MAXB];
    #pragma unroll
    for (int j = 0; j < MAXB; ++j) {
        const int pos = h + 4 * j;
        float4 val = make_float4(0.f, 0.f, 0.f, 0.f);
        if (pos < nbT) {
            const bool f = pos < nb0;
            const int row = f ? R0 : R1;
            const int cb = (pos - (f ? 0 : nb0)) << 2;
            #pragma unroll
            for (int l = 0; l < 4; ++l) {
                const int c = cb + l;
                if (c < row) {
                    const int ir = idxL[row], ic = idxL[c];
                    (&val.x)[l] = 0.5f * (Fs[(size_t)ir * NFM + ic]
                                        - Fs[(size_t)ic * NFM + ir]);
                }
            }
        }
        Lb[j] = val;
    }

    float sgn = 1.0f, la = 0.0f;    // accumulated redundantly on all threads

    for (int k = 0; k < NP; k += 2) {
        const int p = k + 1;
        const int bk = k >> 2, lk = k & 3;   // k even: k,k+1 in same block

        // ---- A: publish columns k (rows>k) and k+1 (rows>k+1) from registers
        if (R0 > k && ((bk & 3) == h)) {
            const int slot = (bk - h) >> 2;
            float4 q = make_float4(0.f, 0.f, 0.f, 0.f);
            #pragma unroll
            for (int j = 0; j < MAXB; ++j) if (j == slot) q = Lb[j];
            ck[R0] = lane_ex(q, lk);
            if (R0 > p) cp[R0] = lane_ex(q, lk + 1);
        }
        if (R1 > k) {
            const int pos = nb0 + bk;
            if ((pos & 3) == h) {
                const int slot = (pos - h) >> 2;
                float4 q = make_float4(0.f, 0.f, 0.f, 0.f);
                #pragma unroll
                for (int j = 0; j < MAXB; ++j) if (j == slot) q = Lb[j];
                ck[R1] = lane_ex(q, lk);
                if (R1 > p) cp[R1] = lane_ex(q, lk + 1);
            }
        }
        __syncthreads();   // BA

        // ---- B: argmax_{r>k} |ck[r]|, carrying signed value (= L[kp][k])
        float bval = -1.0f, bsv = 0.0f; int bidx = 0;
        if (tid > k && tid < NP) {
            const float x = ck[tid];
            bval = fabsf(x); bsv = x; bidx = tid;
        }
        for (int o = 32; o > 0; o >>= 1) {
            const float ov = __shfl_down(bval, o);
            const int   oi = __shfl_down(bidx, o);
            const float os = __shfl_down(bsv, o);
            if (ov > bval || (ov == bval && oi < bidx)) { bval = ov; bidx = oi; bsv = os; }
        }
        if ((tid & 63) == 0) {
            const int w = tid >> 6;
            red[w] = bval; redi[w] = bidx; sred[w] = bsv;
        }
        __syncthreads();   // BB

        float cv = red[0], cs = sred[0]; int ci = redi[0];
        #pragma unroll
        for (int w = 1; w < 8; ++w)
            if (red[w] > cv || (red[w] == cv && redi[w] < ci)) { cv = red[w]; ci = redi[w]; cs = sred[w]; }
        const int kp = ci;
        const float piv = -cs;          // A_post[k][k+1] = -L_pre[kp][k]
        const float rpiv = 1.0f / piv;
        if (kp != p) sgn = -sgn;
        if (piv < 0.0f) sgn = -sgn;
        la += logf(fabsf(piv));
        const bool dopiv = (kp != p);
        const int cq = kp >> 2, kl = kp & 3;

        // ---- C: stage pre-swap row kp (A2) and column kp (A3)
        if (dopiv) {
            if (R0 == kp || R1 == kp) {
                const bool isR0 = (R0 == kp);
                const int rb = isR0 ? 0 : nb0;
                #pragma unroll
                for (int j = 0; j < MAXB; ++j) {
                    const int pos = h + 4 * j;
                    const bool inrow = isR0 ? (pos < nb0) : (pos >= nb0 && pos < nbT);
                    if (inrow) {
                        const int cb = (pos - rb) << 2;
                        #pragma unroll
                        for (int l = 0; l < 4; ++l) {
                            const int c = cb + l;
                            if (c >= p && c < kp) A2[c] = (&Lb[j].x)[l];
                        }
                    }
                }
            }
            if (R0 > kp && ((cq & 3) == h)) {
                const int slot = (cq - h) >> 2; float v = 0.f;
                #pragma unroll
                for (int j = 0; j < MAXB; ++j) if (j == slot) v = lane_ex(Lb[j], kl);
                A3[R0] = v;
            }
            if (R1 > kp) {
                const int pos = nb0 + cq;
                if ((pos & 3) == h) {
                    const int slot = (pos - h) >> 2; float v = 0.f;
                    #pragma unroll
                    for (int j = 0; j < MAXB; ++j) if (j == slot) v = lane_ex(Lb[j], kl);
                    A3[R1] = v;
                }
            }
        }
        __syncthreads();   // BC

        // ---- D: apply the symmetric swap to registers + publish tau/v.
        // Live swap targets only: row kp cols (p,kp): L[kp][c] = -L_pre[c][p]
        //                         col kp rows r>kp:   L[r][kp] = L_pre[r][p]
        if (dopiv) {
            if (R0 == kp || R1 == kp) {
                const bool isR0 = (R0 == kp);
                const int rb = isR0 ? 0 : nb0;
                #pragma unroll
                for (int j = 0; j < MAXB; ++j) {
                    const int pos = h + 4 * j;
                    const bool inrow = isR0 ? (pos < nb0) : (pos >= nb0 && pos < nbT);
                    if (inrow) {
                        const int cb = (pos - rb) << 2;
                        #pragma unroll
                        for (int l = 0; l < 4; ++l) {
                            const int c = cb + l;
                            if (c > p && c < kp) (&Lb[j].x)[l] = -cp[c];
                        }
                    }
                }
            }
            if (R0 > kp && ((cq & 3) == h)) {
                const int slot = (cq - h) >> 2;
                #pragma unroll
                for (int j = 0; j < MAXB; ++j) if (j == slot) {
                    #pragma unroll
                    for (int l = 0; l < 4; ++l) if (l == kl) (&Lb[j].x)[l] = cp[R0];
                }
            }
            if (R1 > kp) {
                const int pos = nb0 + cq;
                if ((pos & 3) == h) {
                    const int slot = (pos - h) >> 2;
                    #pragma unroll
                    for (int j = 0; j < MAXB; ++j) if (j == slot) {
                        #pragma unroll
                        for (int l = 0; l < 4; ++l) if (l == kl) (&Lb[j].x)[l] = cp[R1];
                    }
                }
            }
        }
        {
            const int r = tid;
            if (r >= k + 2 && r < NP) {
                const float t = ((dopiv && r == kp) ? ck[p] : ck[r]) * rpiv;
                float v;
                if (!dopiv)       v = cp[r];
                else if (r < kp)  v = -A2[r];
                else if (r == kp) v = -A2[p];
                else              v = A3[r];
                tv[2 * r] = t; tv[2 * r + 1] = v;
            }
            if (r == k || r == p) { tv[2 * r] = 0.0f; tv[2 * r + 1] = 0.0f; }
        }
        __syncthreads();   // BD

        // ---- E: rank-2 register update: L[r][c] += v[r]*tau[c] - tau[r]*v[c]
        {
            const int c2 = k + 2;
            float tR0 = 0.f, vR0 = 0.f, tR1 = 0.f, vR1 = 0.f;
            if (R0 >= c2) { tR0 = tv[2 * R0]; vR0 = tv[2 * R0 + 1]; }
            if (R1 >= c2) { tR1 = tv[2 * R1]; vR1 = tv[2 * R1 + 1]; }
            #pragma unroll
            for (int j = 0; j < MAXB; ++j) {
                const int pos = h + 4 * j;
                if (pos >= nbT) continue;
                const bool f = pos < nb0;
                const int row = f ? R0 : R1;
                const int cb = (pos - (f ? 0 : nb0)) << 2;
                if (row < c2 || cb + 3 < c2) continue;      // dead block
                const float tr = f ? tR0 : tR1;
                const float vr = f ? vR0 : vR1;
                const float4 q0 = *(const float4*)(tv + 2 * cb);
                const float4 q1 = *(const float4*)(tv + 2 * cb + 4);
                float4 l = Lb[j];
                l.x += vr * q0.x - tr * q0.y;
                l.y += vr * q0.z - tr * q0.w;
                l.z += vr * q1.x - tr * q1.y;
                l.w += vr * q1.z - tr * q1.w;
                Lb[j] = l;
            }
        }
        __syncthreads();   // BE
    }

    if (tid == 0) {
        ws[bid * 2 + 0] = sgn;
        ws[bid * 2 + 1] = la;
    }
}

extern "C" __global__ void MultiPf_combine_kernel(const float* __restrict__ ws,
                                                  float* __restrict__ out)
{
    int b = threadIdx.x + blockIdx.x * blockDim.x;
    if (b >= BATCH) return;
    float sg[NPFS], lg[NPFS];
    float m = -INFINITY;
    for (int j = 0; j < NPFS; ++j) {
        sg[j] = ws[(b * NPFS + j) * 2 + 0];
        lg[j] = ws[(b * NPFS + j) * 2 + 1];
        m = fmaxf(m, lg[j]);
    }
    float val = 0.0f;
    for (int j = 0; j < NPFS; ++j)
        val += sg[j] * expf(lg[j] - m);
    float osgn = (val > 0.0f) ? 1.0f : ((val < 0.0f) ? -1.0f : 0.0f);
    out[b]         = osgn;
    out[BATCH + b] = m + logf(fabsf(val));
}

extern "C" void kernel_launch(void* const* d_in, const int* in_sizes, int n_in,
                              void* d_out, int out_size, void* d_ws, size_t ws_size,
                              hipStream_t stream)
{
    (void)in_sizes; (void)n_in; (void)out_size; (void)ws_size;
    const float* F   = (const float*)d_in[0];
    const int*   idx = (const int*)d_in[1];
    float* out = (float*)d_out;
    float* ws  = (float*)d_ws;

    MultiPf_32469952758284_kernel<<<NBLK, THREADS, 0, stream>>>(F, idx, ws);
    MultiPf_combine_kernel<<<1, 128, 0, stream>>>(ws, out);
}